// Round 1
// 101.406 us; speedup vs baseline: 1.0596x; 1.0596x over previous
//
#include <hip/hip_runtime.h>

// B=16, N=1024, M=8192.
//   d[b,n,m] = || binder[b,n,:] - target[m,:] ||
//   attract[b] = mean of 204 smallest (min_m d) over n;  repel[b] = sum relu(3-d)^2
//   out[b] = 10*attract + 5*repel
//
// R4 changes (R3 post-mortem: pair kernel VALU-bound at 73% busy; inner loop
// paid 6 VALU/pair for d^2 plus a 47%-taken 4-sqrt clash branch):
//  - e-space: stage (-2*t, ||t||^2) in LDS; e = fma(x,-2tx, fma(y,-2ty, fma(z,-2tz, tt)))
//    = ||t||^2 - 2 b.t  -> 3 fma + 1 min per pair. d^2 = ||b||^2 + e with ||b||^2
//    loop-invariant, so the running min folds in e-space (shift commutes with min).
//  - global fold: atomicMin on order-preserving key of e (e can be negative);
//    reduce kernel recomputes ||b||^2 from binder and adds it back pre-selection.
//  - clash: per-POINT __any(e_i < 9-bb_i) (64-pair granularity, ~15% taken,
//    1 sqrt/hit) instead of per-4-point (256-pair, ~47% taken, 4 sqrt/hit).
//  - reduce: radix-256 scan via intra-wave __shfl_up (no barriers) + 4-wave
//    combine: 4 barriers/round instead of 16.

#define BB 16
#define NN 1024
#define MM 8192
#define MT 64           // targets per chunk
#define MC (MM / MT)    // 128 m-chunks
#define KSEL 204        // int(0.2 * 1024)

// order-preserving uint key for float (ascending); memset 0xFF == +inf key
__device__ __forceinline__ unsigned fkey(float f) {
    const unsigned u = __float_as_uint(f);
    return u ^ ((unsigned)((int)u >> 31) | 0x80000000u);
}

__global__ __launch_bounds__(256, 8) void binder_pair_kernel(
    const float* __restrict__ binder,   // [B, N, 3]
    const float* __restrict__ target,   // [M, 3]
    unsigned* __restrict__ min_u,       // [B, N] key of min e (pre-init 0xFFFFFFFF)
    float* __restrict__ repel_part)     // [B, MC]
{
    __shared__ float4 t4[MT];           // (-2tx, -2ty, -2tz, ||t||^2)
    __shared__ float wred[4];

    const int mc  = blockIdx.x;
    const int b   = blockIdx.y;
    const int tid = threadIdx.x;

    if (tid < MT) {
        const float* tp = target + (size_t)(mc * MT + tid) * 3;
        const float tx = tp[0], ty = tp[1], tz = tp[2];
        t4[tid] = make_float4(-2.0f * tx, -2.0f * ty, -2.0f * tz,
                              fmaf(tx, tx, fmaf(ty, ty, tz * tz)));
    }
    __syncthreads();

    // 4 binder points per thread; 48B contiguous/lane, 16B-aligned.
    const float* bp = binder + ((size_t)b * NN + tid * 4) * 3;
    const float4 f0 = ((const float4*)bp)[0];
    const float4 f1 = ((const float4*)bp)[1];
    const float4 f2 = ((const float4*)bp)[2];
    const float x0 = f0.x, y0 = f0.y, z0 = f0.z;
    const float x1 = f0.w, y1 = f1.x, z1 = f1.y;
    const float x2 = f1.z, y2 = f1.w, z2 = f2.x;
    const float x3 = f2.y, y3 = f2.z, z3 = f2.w;

    const float bb0 = fmaf(x0, x0, fmaf(y0, y0, z0 * z0));
    const float bb1 = fmaf(x1, x1, fmaf(y1, y1, z1 * z1));
    const float bb2 = fmaf(x2, x2, fmaf(y2, y2, z2 * z2));
    const float bb3 = fmaf(x3, x3, fmaf(y3, y3, z3 * z3));
    const float th0 = 9.0f - bb0, th1 = 9.0f - bb1;
    const float th2 = 9.0f - bb2, th3 = 9.0f - bb3;

    float m0 = 3.4e38f, m1 = 3.4e38f, m2 = 3.4e38f, m3 = 3.4e38f;
    float repel = 0.0f;

#pragma unroll 4
    for (int m = 0; m < MT; ++m) {
        const float4 t = t4[m];   // wave-uniform addr -> broadcast b128
        const float e0 = fmaf(x0, t.x, fmaf(y0, t.y, fmaf(z0, t.z, t.w)));
        const float e1 = fmaf(x1, t.x, fmaf(y1, t.y, fmaf(z1, t.z, t.w)));
        const float e2 = fmaf(x2, t.x, fmaf(y2, t.y, fmaf(z2, t.z, t.w)));
        const float e3 = fmaf(x3, t.x, fmaf(y3, t.y, fmaf(z3, t.z, t.w)));
        m0 = fminf(m0, e0);
        m1 = fminf(m1, e1);
        m2 = fminf(m2, e2);
        m3 = fminf(m3, e3);
        // per-point clash: e < 9 - bb  <=>  d^2 < 9. Non-clash lanes inside a
        // taken branch compute c = 0 (clamped), so result is exact.
        if (__any(e0 < th0)) {
            const float c = fmaxf(3.0f - __builtin_amdgcn_sqrtf(fmaxf(bb0 + e0, 0.0f)), 0.0f);
            repel = fmaf(c, c, repel);
        }
        if (__any(e1 < th1)) {
            const float c = fmaxf(3.0f - __builtin_amdgcn_sqrtf(fmaxf(bb1 + e1, 0.0f)), 0.0f);
            repel = fmaf(c, c, repel);
        }
        if (__any(e2 < th2)) {
            const float c = fmaxf(3.0f - __builtin_amdgcn_sqrtf(fmaxf(bb2 + e2, 0.0f)), 0.0f);
            repel = fmaf(c, c, repel);
        }
        if (__any(e3 < th3)) {
            const float c = fmaxf(3.0f - __builtin_amdgcn_sqrtf(fmaxf(bb3 + e3, 0.0f)), 0.0f);
            repel = fmaf(c, c, repel);
        }
    }

    // fold chunk e-mins via deterministic uint atomicMin on order-preserving key
    unsigned* mp = min_u + (size_t)b * NN + tid * 4;
    atomicMin(&mp[0], fkey(m0));
    atomicMin(&mp[1], fkey(m1));
    atomicMin(&mp[2], fkey(m2));
    atomicMin(&mp[3], fkey(m3));

    // repel block-reduce: wave shuffle then 4-slot LDS
#pragma unroll
    for (int off = 32; off > 0; off >>= 1) repel += __shfl_down(repel, off);
    if ((tid & 63) == 0) wred[tid >> 6] = repel;
    __syncthreads();
    if (tid == 0) repel_part[b * MC + mc] = wred[0] + wred[1] + wred[2] + wred[3];
}

__global__ __launch_bounds__(256) void binder_reduce_kernel(
    const float* __restrict__ binder,      // [B, N, 3] (to rebuild ||b||^2)
    const unsigned* __restrict__ min_u,    // [B, N] keys of min e
    const float* __restrict__ repel_part,  // [B, MC]
    float* __restrict__ out)               // [B]
{
    __shared__ int cnt[256];
    __shared__ int wsum[4];
    __shared__ int bc_bin, bc_rem;
    __shared__ float wred[4];
    __shared__ float wred2[4];

    const int b    = blockIdx.x;
    const int tid  = threadIdx.x;
    const int lane = tid & 63;
    const int wid  = tid >> 6;

    // keys -> e -> d^2 bits (d^2 >= 0 after clamp, so raw bits are monotonic)
    const uint4 kv = ((const uint4*)(min_u + (size_t)b * NN))[tid];
    const float* bp = binder + ((size_t)b * NN + tid * 4) * 3;
    const float4 f0 = ((const float4*)bp)[0];
    const float4 f1 = ((const float4*)bp)[1];
    const float4 f2 = ((const float4*)bp)[2];
    const float bb0 = fmaf(f0.x, f0.x, fmaf(f0.y, f0.y, f0.z * f0.z));
    const float bb1 = fmaf(f0.w, f0.w, fmaf(f1.x, f1.x, f1.y * f1.y));
    const float bb2 = fmaf(f1.z, f1.z, fmaf(f1.w, f1.w, f2.x * f2.x));
    const float bb3 = fmaf(f2.y, f2.y, fmaf(f2.z, f2.z, f2.w * f2.w));

    unsigned uu[4];
    {
        const unsigned kk[4] = {kv.x, kv.y, kv.z, kv.w};
        const float bbv[4] = {bb0, bb1, bb2, bb3};
#pragma unroll
        for (int p = 0; p < 4; ++p) {
            const unsigned k  = kk[p];
            const unsigned ue = (k & 0x80000000u) ? (k ^ 0x80000000u) : ~k;  // inverse fkey
            const float d2 = fmaxf(bbv[p] + __uint_as_float(ue), 0.0f);
            uu[p] = __float_as_uint(d2);
        }
    }

    // radix-256 select of the KSEL-th smallest d^2 bit pattern, MSB-first.
    // scan per round: intra-wave __shfl_up inclusive scan (no barriers) +
    // 4-entry wave-sum combine -> 4 barriers/round.
    unsigned prefix = 0u;
    int rem = KSEL;
#pragma unroll
    for (int shift = 24; shift >= 0; shift -= 8) {
        cnt[tid] = 0;
        __syncthreads();
        const unsigned hmask = (shift == 24) ? 0u : (0xFFFFFFFFu << (shift + 8));
#pragma unroll
        for (int p = 0; p < 4; ++p)
            if ((uu[p] & hmask) == (prefix & hmask))
                atomicAdd(&cnt[(uu[p] >> shift) & 255], 1);
        __syncthreads();
        const int orig = cnt[tid];
        int v = orig;
#pragma unroll
        for (int s = 1; s < 64; s <<= 1) {
            const int t = __shfl_up(v, s);
            if (lane >= s) v += t;
        }
        if (lane == 63) wsum[wid] = v;
        __syncthreads();
        int off = 0;
        for (int w = 0; w < wid; ++w) off += wsum[w];
        const int incl = v + off;
        const int excl = incl - orig;
        if (rem > excl && rem <= incl) {   // unique tid (orig>0 there)
            bc_bin = tid;
            bc_rem = rem - excl;
        }
        __syncthreads();
        prefix |= ((unsigned)bc_bin) << shift;
        rem = bc_rem;
        __syncthreads();
    }
    // prefix = T (exact bits of KSEL-th smallest d2); rem = #ties to take.

    float local = 0.0f;
#pragma unroll
    for (int p = 0; p < 4; ++p)
        if (uu[p] < prefix) local += __builtin_amdgcn_sqrtf(__uint_as_float(uu[p]));
#pragma unroll
    for (int off = 32; off > 0; off >>= 1) local += __shfl_down(local, off);
    if ((tid & 63) == 0) wred[tid >> 6] = local;

    float r = (tid < MC) ? repel_part[b * MC + tid] : 0.0f;
#pragma unroll
    for (int off = 32; off > 0; off >>= 1) r += __shfl_down(r, off);
    if ((tid & 63) == 0) wred2[tid >> 6] = r;
    __syncthreads();

    if (tid == 0) {
        const float total = wred[0] + wred[1] + wred[2] + wred[3]
                          + (float)rem * __builtin_amdgcn_sqrtf(__uint_as_float(prefix));
        const float rp = wred2[0] + wred2[1] + wred2[2] + wred2[3];
        out[b] = 10.0f * (total / (float)KSEL) + 5.0f * rp;
    }
}

extern "C" void kernel_launch(void* const* d_in, const int* in_sizes, int n_in,
                              void* d_out, int out_size, void* d_ws, size_t ws_size,
                              hipStream_t stream) {
    const float* binder = (const float*)d_in[0];   // [16,1024,3] fp32
    const float* target = (const float*)d_in[1];   // [8192,3]   fp32
    float* out = (float*)d_out;                    // [16]       fp32

    unsigned* min_u   = (unsigned*)d_ws;                               // 64 KB
    float* repel_part = (float*)((char*)d_ws + (size_t)BB * NN * sizeof(unsigned));

    // 0xFFFFFFFF == max key for the atomicMin fold (capture-safe memset)
    hipMemsetAsync(min_u, 0xFF, (size_t)BB * NN * sizeof(unsigned), stream);

    dim3 g1(MC, BB);   // 128 x 16 = 2048 blocks -> 8 blocks/CU
    binder_pair_kernel<<<g1, 256, 0, stream>>>(binder, target, min_u, repel_part);
    binder_reduce_kernel<<<BB, 256, 0, stream>>>(binder, min_u, repel_part, out);
}